// Round 1
// baseline (658.980 us; speedup 1.0000x reference)
//
#include <hip/hip_runtime.h>

// MoE: T=8192 tokens, D_MODEL=1024, D_FF=1024, E=8, top-2.
// Router fp32 (selection must match np ref); expert FFN bf16 MFMA.

#define T_TOK   8192
#define DM      1024
#define DFF     1024
#define NE      8
#define CAP     16384          // worst-case rows per expert
#define LDA     88             // LDS row stride (ushorts): 176B = 16B-aligned, 2-way banks only

typedef __attribute__((ext_vector_type(8))) short bf16x8;
typedef __attribute__((ext_vector_type(4))) float f32x4;

__device__ __forceinline__ unsigned short f2bf(float f) {
    union { float f; unsigned u; } c; c.f = f;
    unsigned r = c.u + 0x7fffu + ((c.u >> 16) & 1u);
    return (unsigned short)(r >> 16);
}

// ---------------- fp32 -> bf16 bits ----------------
__global__ __launch_bounds__(256) void cvt_kernel(const float* __restrict__ src,
                                                  unsigned short* __restrict__ dst, int n) {
    int i = (blockIdx.x * 256 + threadIdx.x) * 4;
    if (i >= n) return;
    float4 v = *(const float4*)(src + i);
    ushort4 o;
    o.x = f2bf(v.x); o.y = f2bf(v.y); o.z = f2bf(v.z); o.w = f2bf(v.w);
    *(ushort4*)(dst + i) = o;
}

// ---------------- router (fp32) ----------------
// one wave per token; gate_w staged in LDS (32 KB)
__global__ __launch_bounds__(256) void router_kernel(
    const float* __restrict__ x, const float* __restrict__ gate_w,
    int* __restrict__ elist, float* __restrict__ wlist,
    int* __restrict__ ecnt, float* __restrict__ psum)
{
    __shared__ float gw[NE * DM];
    __shared__ float blk_psum[NE];
    int tid = threadIdx.x;
    for (int i = tid; i < NE * DM; i += 256) gw[i] = gate_w[i];
    if (tid < NE) blk_psum[tid] = 0.f;
    __syncthreads();

    int wv = tid >> 6, lane = tid & 63;
    int t = blockIdx.x * 4 + wv;          // grid = T/4 blocks, always in range

    float acc[NE];
    #pragma unroll
    for (int e = 0; e < NE; ++e) acc[e] = 0.f;
    const float* xr = x + (size_t)t * DM;
    #pragma unroll 4
    for (int i = 0; i < DM / 64; ++i) {
        float xv = xr[i * 64 + lane];
        #pragma unroll
        for (int e = 0; e < NE; ++e)
            acc[e] += xv * gw[e * DM + i * 64 + lane];
    }
    #pragma unroll
    for (int e = 0; e < NE; ++e) {
        float v = acc[e];
        #pragma unroll
        for (int s = 32; s > 0; s >>= 1) v += __shfl_xor(v, s, 64);
        acc[e] = v;
    }
    if (lane == 0) {
        float mx = acc[0];
        #pragma unroll
        for (int e = 1; e < NE; ++e) mx = fmaxf(mx, acc[e]);
        float p[NE], sum = 0.f;
        #pragma unroll
        for (int e = 0; e < NE; ++e) { p[e] = expf(acc[e] - mx); sum += p[e]; }
        float inv = 1.f / sum;
        #pragma unroll
        for (int e = 0; e < NE; ++e) { p[e] *= inv; atomicAdd(&blk_psum[e], p[e]); }
        // top-2, ties -> lowest index (strict >)
        int i1 = 0; float v1 = p[0];
        #pragma unroll
        for (int e = 1; e < NE; ++e) if (p[e] > v1) { v1 = p[e]; i1 = e; }
        int i2 = -1; float v2 = -1.f;
        #pragma unroll
        for (int e = 0; e < NE; ++e) { if (e == i1) continue; if (p[e] > v2) { v2 = p[e]; i2 = e; } }
        float winv = 1.f / (v1 + v2);
        int pos1 = atomicAdd(&ecnt[i1], 1);
        elist[i1 * CAP + pos1] = t * 2 + 0;
        wlist[i1 * CAP + pos1] = v1 * winv;
        int pos2 = atomicAdd(&ecnt[i2], 1);
        elist[i2 * CAP + pos2] = t * 2 + 1;
        wlist[i2 * CAP + pos2] = v2 * winv;
    }
    __syncthreads();
    if (tid < NE) atomicAdd(&psum[tid], blk_psum[tid]);
}

// ---------------- aux loss + counts -> output tail ----------------
__global__ void finalize_kernel(const int* __restrict__ ecnt, const float* __restrict__ psum,
                                float* __restrict__ out_tail)
{
    __shared__ float parts[NE];
    int e = threadIdx.x;
    if (e < NE) {
        float f = (float)ecnt[e] / (float)(2 * T_TOK);
        float P = psum[e] / (float)T_TOK;
        parts[e] = f * P;
        out_tail[1 + e] = (float)ecnt[e];
    }
    __syncthreads();
    if (e == 0) {
        float s = 0.f;
        for (int i = 0; i < NE; ++i) s += parts[i];
        out_tail[0] = (float)NE * s;
    }
}

// ---------------- GEMM1: H[ts][f] = silu(Xg)·Xu  (gathered rows) ----------------
// grid (F/64, CAP/64, NE); block 256 (4 waves); tile 64x64x(K=1024), BK=64
__global__ __launch_bounds__(256) void gemm1_kernel(
    const unsigned short* __restrict__ xb,   // [T][DM] bf16
    const unsigned short* __restrict__ wgb,  // [NE][DFF][DM]
    const unsigned short* __restrict__ wub,
    const int* __restrict__ elist, const int* __restrict__ ecnt,
    unsigned short* __restrict__ Hbuf)       // [2T][DFF]
{
    int e = blockIdx.z, mt = blockIdx.y, ft = blockIdx.x;
    int ne = ecnt[e];
    if (mt * 64 >= ne) return;

    __shared__ unsigned short As[64][LDA];
    __shared__ unsigned short Gs[64][LDA];
    __shared__ unsigned short Us[64][LDA];
    __shared__ int rowts[64];

    int tid = threadIdx.x;
    if (tid < 64) {
        int pos = mt * 64 + tid;
        rowts[tid] = (pos < ne) ? elist[e * CAP + pos] : -1;
    }
    __syncthreads();

    int wv = tid >> 6, lane = tid & 63;
    int quad = lane >> 4, col = lane & 15;
    int r0 = tid >> 3;            // 0..31 (rows r0, r0+32)
    int c0 = (tid & 7) * 8;       // element col in 64-chunk

    const size_t woff = (size_t)e * DFF * DM;
    f32x4 accG[4], accU[4];
    #pragma unroll
    for (int n = 0; n < 4; ++n) { accG[n] = (f32x4){0,0,0,0}; accU[n] = (f32x4){0,0,0,0}; }

    for (int k0 = 0; k0 < DM; k0 += 64) {
        #pragma unroll
        for (int rr = 0; rr < 2; ++rr) {
            int row = r0 + rr * 32;
            int ts = rowts[row];
            uint4 av = make_uint4(0, 0, 0, 0);
            if (ts >= 0) av = *(const uint4*)(xb + (size_t)(ts >> 1) * DM + k0 + c0);
            *(uint4*)&As[row][c0] = av;
            *(uint4*)&Gs[row][c0] = *(const uint4*)(wgb + woff + (size_t)(ft * 64 + row) * DM + k0 + c0);
            *(uint4*)&Us[row][c0] = *(const uint4*)(wub + woff + (size_t)(ft * 64 + row) * DM + k0 + c0);
        }
        __syncthreads();
        #pragma unroll
        for (int ks = 0; ks < 64; ks += 32) {
            bf16x8 a = *(const bf16x8*)&As[wv * 16 + col][ks + quad * 8];
            #pragma unroll
            for (int n = 0; n < 4; ++n) {
                bf16x8 g = *(const bf16x8*)&Gs[n * 16 + col][ks + quad * 8];
                bf16x8 u = *(const bf16x8*)&Us[n * 16 + col][ks + quad * 8];
                accG[n] = __builtin_amdgcn_mfma_f32_16x16x32_bf16(a, g, accG[n], 0, 0, 0);
                accU[n] = __builtin_amdgcn_mfma_f32_16x16x32_bf16(a, u, accU[n], 0, 0, 0);
            }
        }
        __syncthreads();
    }
    // epilogue: silu(g)*u -> Hbuf[ts][ft*64 + n*16 + col]
    #pragma unroll
    for (int n = 0; n < 4; ++n) {
        #pragma unroll
        for (int r = 0; r < 4; ++r) {
            int row = wv * 16 + quad * 4 + r;
            int ts = rowts[row];
            if (ts < 0) continue;
            float g = accG[n][r], u = accU[n][r];
            float h = (g / (1.f + expf(-g))) * u;
            Hbuf[(size_t)ts * DFF + ft * 64 + n * 16 + col] = f2bf(h);
        }
    }
}

// ---------------- GEMM2: out[t] += w * (H @ Wd^T) ----------------
__global__ __launch_bounds__(256) void gemm2_kernel(
    const unsigned short* __restrict__ Hbuf, // [2T][DFF]
    const unsigned short* __restrict__ wdb,  // [NE][DM][DFF]
    const int* __restrict__ elist, const float* __restrict__ wlist,
    const int* __restrict__ ecnt, float* __restrict__ out)
{
    int e = blockIdx.z, mt = blockIdx.y, dt = blockIdx.x;
    int ne = ecnt[e];
    if (mt * 64 >= ne) return;

    __shared__ unsigned short As[64][LDA];
    __shared__ unsigned short Bs[64][LDA];
    __shared__ int rowts[64];
    __shared__ float roww[64];

    int tid = threadIdx.x;
    if (tid < 64) {
        int pos = mt * 64 + tid;
        int v = (pos < ne) ? elist[e * CAP + pos] : -1;
        rowts[tid] = v;
        roww[tid] = (pos < ne) ? wlist[e * CAP + pos] : 0.f;
    }
    __syncthreads();

    int wv = tid >> 6, lane = tid & 63;
    int quad = lane >> 4, col = lane & 15;
    int r0 = tid >> 3;
    int c0 = (tid & 7) * 8;

    const size_t woff = (size_t)e * DM * DFF;
    f32x4 acc[4];
    #pragma unroll
    for (int n = 0; n < 4; ++n) acc[n] = (f32x4){0,0,0,0};

    for (int k0 = 0; k0 < DFF; k0 += 64) {
        #pragma unroll
        for (int rr = 0; rr < 2; ++rr) {
            int row = r0 + rr * 32;
            int ts = rowts[row];
            uint4 av = make_uint4(0, 0, 0, 0);
            if (ts >= 0) av = *(const uint4*)(Hbuf + (size_t)ts * DFF + k0 + c0);
            *(uint4*)&As[row][c0] = av;
            *(uint4*)&Bs[row][c0] = *(const uint4*)(wdb + woff + (size_t)(dt * 64 + row) * DFF + k0 + c0);
        }
        __syncthreads();
        #pragma unroll
        for (int ks = 0; ks < 64; ks += 32) {
            bf16x8 a = *(const bf16x8*)&As[wv * 16 + col][ks + quad * 8];
            #pragma unroll
            for (int n = 0; n < 4; ++n) {
                bf16x8 b = *(const bf16x8*)&Bs[n * 16 + col][ks + quad * 8];
                acc[n] = __builtin_amdgcn_mfma_f32_16x16x32_bf16(a, b, acc[n], 0, 0, 0);
            }
        }
        __syncthreads();
    }
    #pragma unroll
    for (int n = 0; n < 4; ++n) {
        #pragma unroll
        for (int r = 0; r < 4; ++r) {
            int row = wv * 16 + quad * 4 + r;
            int ts = rowts[row];
            if (ts < 0) continue;
            int t = ts >> 1;
            atomicAdd(&out[(size_t)t * DM + dt * 64 + n * 16 + col], roww[row] * acc[n][r]);
        }
    }
}

extern "C" void kernel_launch(void* const* d_in, const int* in_sizes, int n_in,
                              void* d_out, int out_size, void* d_ws, size_t ws_size,
                              hipStream_t stream) {
    const float* x      = (const float*)d_in[0];
    const float* gate_w = (const float*)d_in[1];
    const float* w_gate = (const float*)d_in[2];
    const float* w_up   = (const float*)d_in[3];
    const float* w_down = (const float*)d_in[4];
    float* out = (float*)d_out;

    // workspace carve-up (~102 MB)
    char* p = (char*)d_ws;
    unsigned short* xb   = (unsigned short*)p; p += (size_t)T_TOK * DM * 2;
    unsigned short* wgb  = (unsigned short*)p; p += (size_t)NE * DFF * DM * 2;
    unsigned short* wub  = (unsigned short*)p; p += (size_t)NE * DFF * DM * 2;
    unsigned short* wdb  = (unsigned short*)p; p += (size_t)NE * DM * DFF * 2;
    unsigned short* Hbuf = (unsigned short*)p; p += (size_t)2 * T_TOK * DFF * 2;
    int*   elist = (int*)p;   p += (size_t)NE * CAP * 4;
    float* wlist = (float*)p; p += (size_t)NE * CAP * 4;
    int*   ecnt  = (int*)p;   p += NE * 4;
    float* psum  = (float*)p; p += NE * 4;

    hipMemsetAsync(d_out, 0, (size_t)out_size * 4, stream);
    hipMemsetAsync(ecnt, 0, 2 * NE * 4, stream);   // ecnt + psum (contiguous)

    const int nW = NE * DFF * DM;
    cvt_kernel<<<(T_TOK * DM / 4 + 255) / 256, 256, 0, stream>>>(x, xb, T_TOK * DM);
    cvt_kernel<<<(nW / 4 + 255) / 256, 256, 0, stream>>>(w_gate, wgb, nW);
    cvt_kernel<<<(nW / 4 + 255) / 256, 256, 0, stream>>>(w_up, wub, nW);
    cvt_kernel<<<(nW / 4 + 255) / 256, 256, 0, stream>>>(w_down, wdb, nW);

    router_kernel<<<T_TOK / 4, 256, 0, stream>>>(x, gate_w, elist, wlist, ecnt, psum);
    finalize_kernel<<<1, 64, 0, stream>>>(ecnt, psum, out + (size_t)T_TOK * DM);

    gemm1_kernel<<<dim3(DFF / 64, CAP / 64, NE), 256, 0, stream>>>(xb, wgb, wub, elist, ecnt, Hbuf);
    gemm2_kernel<<<dim3(DM / 64, CAP / 64, NE), 256, 0, stream>>>(Hbuf, wdb, elist, wlist, ecnt, out);
}

// Round 2
// 464.857 us; speedup vs baseline: 1.4176x; 1.4176x over previous
//
#include <hip/hip_runtime.h>

// MoE: T=8192 tokens, D_MODEL=1024, D_FF=1024, E=8, top-2.
// Router fp32 (selection must match np ref); expert FFN bf16 MFMA.
// R2: hierarchical scatter — no contended returning atomics.

#define T_TOK   8192
#define DM      1024
#define DFF     1024
#define NE      8
#define CAP     16384          // worst-case rows per expert
#define LDA     88             // LDS row stride (ushorts): 176B = 16B-aligned, 2-way banks only
#define R1_BLK  (T_TOK / 4)    // 2048 router blocks, 4 tokens each

typedef __attribute__((ext_vector_type(8))) short bf16x8;
typedef __attribute__((ext_vector_type(4))) float f32x4;

__device__ __forceinline__ unsigned short f2bf(float f) {
    union { float f; unsigned u; } c; c.f = f;
    unsigned r = c.u + 0x7fffu + ((c.u >> 16) & 1u);
    return (unsigned short)(r >> 16);
}

// ---------------- fp32 -> bf16 bits (weights) ----------------
__global__ __launch_bounds__(256) void cvt_kernel(const float* __restrict__ src,
                                                  unsigned short* __restrict__ dst, int n) {
    int i = (blockIdx.x * 256 + threadIdx.x) * 4;
    if (i >= n) return;
    float4 v = *(const float4*)(src + i);
    ushort4 o;
    o.x = f2bf(v.x); o.y = f2bf(v.y); o.z = f2bf(v.z); o.w = f2bf(v.w);
    *(ushort4*)(dst + i) = o;
}

// ---------------- R1: router math (fp32) + x->bf16 fuse ----------------
// one wave per token; gate_w staged in LDS (32 KB); NO contended atomics.
__global__ __launch_bounds__(256) void router_kernel(
    const float* __restrict__ x, const float* __restrict__ gate_w,
    unsigned short* __restrict__ xb,
    int* __restrict__ topi, float2* __restrict__ topw,
    float* __restrict__ psum_part)
{
    __shared__ float gw[NE * DM];
    __shared__ float blk_psum[NE];
    int tid = threadIdx.x;
    for (int i = tid; i < NE * DM; i += 256) gw[i] = gate_w[i];
    if (tid < NE) blk_psum[tid] = 0.f;
    __syncthreads();

    int wv = tid >> 6, lane = tid & 63;
    int t = blockIdx.x * 4 + wv;          // grid = T/4 blocks, always in range

    float acc[NE];
    #pragma unroll
    for (int e = 0; e < NE; ++e) acc[e] = 0.f;
    const float* xr = x + (size_t)t * DM;
    unsigned short* xbr = xb + (size_t)t * DM;
    #pragma unroll 4
    for (int i = 0; i < DM / 64; ++i) {
        float xv = xr[i * 64 + lane];
        xbr[i * 64 + lane] = f2bf(xv);
        #pragma unroll
        for (int e = 0; e < NE; ++e)
            acc[e] += xv * gw[e * DM + i * 64 + lane];
    }
    #pragma unroll
    for (int e = 0; e < NE; ++e) {
        float v = acc[e];
        #pragma unroll
        for (int s = 32; s > 0; s >>= 1) v += __shfl_xor(v, s, 64);
        acc[e] = v;
    }
    if (lane == 0) {
        float mx = acc[0];
        #pragma unroll
        for (int e = 1; e < NE; ++e) mx = fmaxf(mx, acc[e]);
        float p[NE], sum = 0.f;
        #pragma unroll
        for (int e = 0; e < NE; ++e) { p[e] = expf(acc[e] - mx); sum += p[e]; }
        float inv = 1.f / sum;
        #pragma unroll
        for (int e = 0; e < NE; ++e) { p[e] *= inv; atomicAdd(&blk_psum[e], p[e]); }
        // top-2, ties -> lowest index (strict >)
        int i1 = 0; float v1 = p[0];
        #pragma unroll
        for (int e = 1; e < NE; ++e) if (p[e] > v1) { v1 = p[e]; i1 = e; }
        int i2 = -1; float v2 = -1.f;
        #pragma unroll
        for (int e = 0; e < NE; ++e) { if (e == i1) continue; if (p[e] > v2) { v2 = p[e]; i2 = e; } }
        float winv = 1.f / (v1 + v2);
        topi[t] = i1 | (i2 << 8);
        topw[t] = make_float2(v1 * winv, v2 * winv);
    }
    __syncthreads();
    if (tid < NE) psum_part[blockIdx.x * NE + tid] = blk_psum[tid];
}

// ---------------- R2: scatter into per-expert lists ----------------
// 32 blocks x 256 tokens; 8 returning global atomics per block total.
__global__ __launch_bounds__(256) void scatter_kernel(
    const int* __restrict__ topi, const float2* __restrict__ topw,
    int* __restrict__ elist, float* __restrict__ wlist, int* __restrict__ ecnt)
{
    __shared__ int lcnt[NE];
    __shared__ int lbase[NE];
    int tid = threadIdx.x;
    if (tid < NE) lcnt[tid] = 0;
    __syncthreads();
    int t = blockIdx.x * 256 + tid;
    int pk = topi[t];
    float2 w = topw[t];
    int e1 = pk & 0xff, e2 = (pk >> 8) & 0xff;
    int p1 = atomicAdd(&lcnt[e1], 1);
    int p2 = atomicAdd(&lcnt[e2], 1);
    __syncthreads();
    if (tid < NE) lbase[tid] = atomicAdd(&ecnt[tid], lcnt[tid]);
    __syncthreads();
    int o1 = lbase[e1] + p1;
    elist[e1 * CAP + o1] = t * 2 + 0;
    wlist[e1 * CAP + o1] = w.x;
    int o2 = lbase[e2] + p2;
    elist[e2 * CAP + o2] = t * 2 + 1;
    wlist[e2 * CAP + o2] = w.y;
}

// ---------------- finalize: psum reduce + aux loss + counts ----------------
__global__ __launch_bounds__(256) void finalize_kernel(
    const int* __restrict__ ecnt, const float* __restrict__ psum_part,
    float* __restrict__ out_tail)
{
    __shared__ float red[256];
    __shared__ float parts[NE];
    int tid = threadIdx.x;
    int e = tid & 7, b0 = tid >> 3;     // 32 threads per expert
    float s = 0.f;
    for (int b = b0; b < R1_BLK; b += 32) s += psum_part[b * NE + e];
    red[tid] = s;
    __syncthreads();
    if (tid < NE) {
        float tot = 0.f;
        #pragma unroll
        for (int j = 0; j < 32; ++j) tot += red[tid + NE * j];
        float P = tot / (float)T_TOK;
        float f = (float)ecnt[tid] / (float)(2 * T_TOK);
        parts[tid] = f * P;
        out_tail[1 + tid] = (float)ecnt[tid];
    }
    __syncthreads();
    if (tid == 0) {
        float s2 = 0.f;
        for (int i = 0; i < NE; ++i) s2 += parts[i];
        out_tail[0] = (float)NE * s2;
    }
}

// ---------------- GEMM1: H[ts][f] = silu(Xg)·Xu  (gathered rows) ----------------
__global__ __launch_bounds__(256) void gemm1_kernel(
    const unsigned short* __restrict__ xb,   // [T][DM] bf16
    const unsigned short* __restrict__ wgb,  // [NE][DFF][DM]
    const unsigned short* __restrict__ wub,
    const int* __restrict__ elist, const int* __restrict__ ecnt,
    unsigned short* __restrict__ Hbuf)       // [2T][DFF]
{
    int e = blockIdx.z, mt = blockIdx.y, ft = blockIdx.x;
    int ne = ecnt[e];
    if (mt * 64 >= ne) return;

    __shared__ unsigned short As[64][LDA];
    __shared__ unsigned short Gs[64][LDA];
    __shared__ unsigned short Us[64][LDA];
    __shared__ int rowts[64];

    int tid = threadIdx.x;
    if (tid < 64) {
        int pos = mt * 64 + tid;
        rowts[tid] = (pos < ne) ? elist[e * CAP + pos] : -1;
    }
    __syncthreads();

    int wv = tid >> 6, lane = tid & 63;
    int quad = lane >> 4, col = lane & 15;
    int r0 = tid >> 3;            // 0..31 (rows r0, r0+32)
    int c0 = (tid & 7) * 8;       // element col in 64-chunk

    const size_t woff = (size_t)e * DFF * DM;
    f32x4 accG[4], accU[4];
    #pragma unroll
    for (int n = 0; n < 4; ++n) { accG[n] = (f32x4){0,0,0,0}; accU[n] = (f32x4){0,0,0,0}; }

    for (int k0 = 0; k0 < DM; k0 += 64) {
        #pragma unroll
        for (int rr = 0; rr < 2; ++rr) {
            int row = r0 + rr * 32;
            int ts = rowts[row];
            uint4 av = make_uint4(0, 0, 0, 0);
            if (ts >= 0) av = *(const uint4*)(xb + (size_t)(ts >> 1) * DM + k0 + c0);
            *(uint4*)&As[row][c0] = av;
            *(uint4*)&Gs[row][c0] = *(const uint4*)(wgb + woff + (size_t)(ft * 64 + row) * DM + k0 + c0);
            *(uint4*)&Us[row][c0] = *(const uint4*)(wub + woff + (size_t)(ft * 64 + row) * DM + k0 + c0);
        }
        __syncthreads();
        #pragma unroll
        for (int ks = 0; ks < 64; ks += 32) {
            bf16x8 a = *(const bf16x8*)&As[wv * 16 + col][ks + quad * 8];
            #pragma unroll
            for (int n = 0; n < 4; ++n) {
                bf16x8 g = *(const bf16x8*)&Gs[n * 16 + col][ks + quad * 8];
                bf16x8 u = *(const bf16x8*)&Us[n * 16 + col][ks + quad * 8];
                accG[n] = __builtin_amdgcn_mfma_f32_16x16x32_bf16(a, g, accG[n], 0, 0, 0);
                accU[n] = __builtin_amdgcn_mfma_f32_16x16x32_bf16(a, u, accU[n], 0, 0, 0);
            }
        }
        __syncthreads();
    }
    #pragma unroll
    for (int n = 0; n < 4; ++n) {
        #pragma unroll
        for (int r = 0; r < 4; ++r) {
            int row = wv * 16 + quad * 4 + r;
            int ts = rowts[row];
            if (ts < 0) continue;
            float g = accG[n][r], u = accU[n][r];
            float h = (g / (1.f + expf(-g))) * u;
            Hbuf[(size_t)ts * DFF + ft * 64 + n * 16 + col] = f2bf(h);
        }
    }
}

// ---------------- GEMM2: out[t] += w * (H @ Wd^T) ----------------
__global__ __launch_bounds__(256) void gemm2_kernel(
    const unsigned short* __restrict__ Hbuf, // [2T][DFF]
    const unsigned short* __restrict__ wdb,  // [NE][DM][DFF]
    const int* __restrict__ elist, const float* __restrict__ wlist,
    const int* __restrict__ ecnt, float* __restrict__ out)
{
    int e = blockIdx.z, mt = blockIdx.y, dt = blockIdx.x;
    int ne = ecnt[e];
    if (mt * 64 >= ne) return;

    __shared__ unsigned short As[64][LDA];
    __shared__ unsigned short Bs[64][LDA];
    __shared__ int rowts[64];
    __shared__ float roww[64];

    int tid = threadIdx.x;
    if (tid < 64) {
        int pos = mt * 64 + tid;
        int v = (pos < ne) ? elist[e * CAP + pos] : -1;
        rowts[tid] = v;
        roww[tid] = (pos < ne) ? wlist[e * CAP + pos] : 0.f;
    }
    __syncthreads();

    int wv = tid >> 6, lane = tid & 63;
    int quad = lane >> 4, col = lane & 15;
    int r0 = tid >> 3;
    int c0 = (tid & 7) * 8;

    const size_t woff = (size_t)e * DM * DFF;
    f32x4 acc[4];
    #pragma unroll
    for (int n = 0; n < 4; ++n) acc[n] = (f32x4){0,0,0,0};

    for (int k0 = 0; k0 < DFF; k0 += 64) {
        #pragma unroll
        for (int rr = 0; rr < 2; ++rr) {
            int row = r0 + rr * 32;
            int ts = rowts[row];
            uint4 av = make_uint4(0, 0, 0, 0);
            if (ts >= 0) av = *(const uint4*)(Hbuf + (size_t)ts * DFF + k0 + c0);
            *(uint4*)&As[row][c0] = av;
            *(uint4*)&Bs[row][c0] = *(const uint4*)(wdb + woff + (size_t)(dt * 64 + row) * DFF + k0 + c0);
        }
        __syncthreads();
        #pragma unroll
        for (int ks = 0; ks < 64; ks += 32) {
            bf16x8 a = *(const bf16x8*)&As[wv * 16 + col][ks + quad * 8];
            #pragma unroll
            for (int n = 0; n < 4; ++n) {
                bf16x8 b = *(const bf16x8*)&Bs[n * 16 + col][ks + quad * 8];
                acc[n] = __builtin_amdgcn_mfma_f32_16x16x32_bf16(a, b, acc[n], 0, 0, 0);
            }
        }
        __syncthreads();
    }
    #pragma unroll
    for (int n = 0; n < 4; ++n) {
        #pragma unroll
        for (int r = 0; r < 4; ++r) {
            int row = wv * 16 + quad * 4 + r;
            int ts = rowts[row];
            if (ts < 0) continue;
            int t = ts >> 1;
            atomicAdd(&out[(size_t)t * DM + dt * 64 + n * 16 + col], roww[row] * acc[n][r]);
        }
    }
}

extern "C" void kernel_launch(void* const* d_in, const int* in_sizes, int n_in,
                              void* d_out, int out_size, void* d_ws, size_t ws_size,
                              hipStream_t stream) {
    const float* x      = (const float*)d_in[0];
    const float* gate_w = (const float*)d_in[1];
    const float* w_gate = (const float*)d_in[2];
    const float* w_up   = (const float*)d_in[3];
    const float* w_down = (const float*)d_in[4];
    float* out = (float*)d_out;

    // workspace carve-up (~102 MB)
    char* p = (char*)d_ws;
    unsigned short* xb   = (unsigned short*)p; p += (size_t)T_TOK * DM * 2;
    unsigned short* wgb  = (unsigned short*)p; p += (size_t)NE * DFF * DM * 2;
    unsigned short* wub  = (unsigned short*)p; p += (size_t)NE * DFF * DM * 2;
    unsigned short* wdb  = (unsigned short*)p; p += (size_t)NE * DM * DFF * 2;
    unsigned short* Hbuf = (unsigned short*)p; p += (size_t)2 * T_TOK * DFF * 2;
    int*   elist = (int*)p;   p += (size_t)NE * CAP * 4;
    float* wlist = (float*)p; p += (size_t)NE * CAP * 4;
    int*   ecnt  = (int*)p;   p += NE * 4;
    int*   topi  = (int*)p;   p += (size_t)T_TOK * 4;
    float2* topw = (float2*)p; p += (size_t)T_TOK * 8;
    float* psum_part = (float*)p; p += (size_t)R1_BLK * NE * 4;

    hipMemsetAsync(d_out, 0, (size_t)out_size * 4, stream);
    hipMemsetAsync(ecnt, 0, NE * 4, stream);

    const int nW = NE * DFF * DM;
    cvt_kernel<<<(nW / 4 + 255) / 256, 256, 0, stream>>>(w_gate, wgb, nW);
    cvt_kernel<<<(nW / 4 + 255) / 256, 256, 0, stream>>>(w_up, wub, nW);
    cvt_kernel<<<(nW / 4 + 255) / 256, 256, 0, stream>>>(w_down, wdb, nW);

    router_kernel<<<R1_BLK, 256, 0, stream>>>(x, gate_w, xb, topi, topw, psum_part);
    scatter_kernel<<<T_TOK / 256, 256, 0, stream>>>(topi, topw, elist, wlist, ecnt);
    finalize_kernel<<<1, 256, 0, stream>>>(ecnt, psum_part, out + (size_t)T_TOK * DM);

    gemm1_kernel<<<dim3(DFF / 64, CAP / 64, NE), 256, 0, stream>>>(xb, wgb, wub, elist, ecnt, Hbuf);
    gemm2_kernel<<<dim3(DM / 64, CAP / 64, NE), 256, 0, stream>>>(Hbuf, wdb, elist, wlist, ecnt, out);
}

// Round 3
// 380.961 us; speedup vs baseline: 1.7298x; 1.2202x over previous
//
#include <hip/hip_runtime.h>

// MoE: T=8192, D_MODEL=1024, D_FF=1024, E=8, top-2.
// Router fp32; expert FFN bf16 MFMA, m97-style: global_load_lds(16B) staging
// + XOR-swizzled unpadded LDS tiles (conflict-free fragment reads).

#define T_TOK   8192
#define DM      1024
#define DFF     1024
#define NE      8
#define CAP     16384
#define R1_BLK  (T_TOK / 4)

typedef __attribute__((ext_vector_type(8))) short bf16x8;
typedef __attribute__((ext_vector_type(4))) float f32x4;

#define ASYNC16(gp, lp) __builtin_amdgcn_global_load_lds( \
    (const __attribute__((address_space(1))) unsigned int*)(gp), \
    (__attribute__((address_space(3))) unsigned int*)(lp), 16, 0, 0)

__device__ __forceinline__ unsigned short f2bf(float f) {
    union { float f; unsigned u; } c; c.f = f;
    unsigned r = c.u + 0x7fffu + ((c.u >> 16) & 1u);
    return (unsigned short)(r >> 16);
}

// ---------------- fp32 -> bf16 bits (weights) ----------------
__global__ __launch_bounds__(256) void cvt_kernel(const float* __restrict__ src,
                                                  unsigned short* __restrict__ dst, int n) {
    int i = (blockIdx.x * 256 + threadIdx.x) * 4;
    if (i >= n) return;
    float4 v = *(const float4*)(src + i);
    ushort4 o;
    o.x = f2bf(v.x); o.y = f2bf(v.y); o.z = f2bf(v.z); o.w = f2bf(v.w);
    *(ushort4*)(dst + i) = o;
}

// ---------------- R1: router math (fp32) + x->bf16 fuse ----------------
__global__ __launch_bounds__(256) void router_kernel(
    const float* __restrict__ x, const float* __restrict__ gate_w,
    unsigned short* __restrict__ xb,
    int* __restrict__ topi, float2* __restrict__ topw,
    float* __restrict__ psum_part)
{
    __shared__ float gw[NE * DM];
    __shared__ float blk_psum[NE];
    int tid = threadIdx.x;
    for (int i = tid; i < NE * DM; i += 256) gw[i] = gate_w[i];
    if (tid < NE) blk_psum[tid] = 0.f;
    __syncthreads();

    int wv = tid >> 6, lane = tid & 63;
    int t = blockIdx.x * 4 + wv;

    float acc[NE];
    #pragma unroll
    for (int e = 0; e < NE; ++e) acc[e] = 0.f;
    const float* xr = x + (size_t)t * DM;
    unsigned short* xbr = xb + (size_t)t * DM;
    #pragma unroll 4
    for (int i = 0; i < DM / 64; ++i) {
        float xv = xr[i * 64 + lane];
        xbr[i * 64 + lane] = f2bf(xv);
        #pragma unroll
        for (int e = 0; e < NE; ++e)
            acc[e] += xv * gw[e * DM + i * 64 + lane];
    }
    #pragma unroll
    for (int e = 0; e < NE; ++e) {
        float v = acc[e];
        #pragma unroll
        for (int s = 32; s > 0; s >>= 1) v += __shfl_xor(v, s, 64);
        acc[e] = v;
    }
    if (lane == 0) {
        float mx = acc[0];
        #pragma unroll
        for (int e = 1; e < NE; ++e) mx = fmaxf(mx, acc[e]);
        float p[NE], sum = 0.f;
        #pragma unroll
        for (int e = 0; e < NE; ++e) { p[e] = expf(acc[e] - mx); sum += p[e]; }
        float inv = 1.f / sum;
        #pragma unroll
        for (int e = 0; e < NE; ++e) { p[e] *= inv; atomicAdd(&blk_psum[e], p[e]); }
        int i1 = 0; float v1 = p[0];
        #pragma unroll
        for (int e = 1; e < NE; ++e) if (p[e] > v1) { v1 = p[e]; i1 = e; }
        int i2 = -1; float v2 = -1.f;
        #pragma unroll
        for (int e = 0; e < NE; ++e) { if (e == i1) continue; if (p[e] > v2) { v2 = p[e]; i2 = e; } }
        float winv = 1.f / (v1 + v2);
        topi[t] = i1 | (i2 << 8);
        topw[t] = make_float2(v1 * winv, v2 * winv);
    }
    __syncthreads();
    if (tid < NE) psum_part[blockIdx.x * NE + tid] = blk_psum[tid];
}

// ---------------- R2: scatter into per-expert lists ----------------
__global__ __launch_bounds__(256) void scatter_kernel(
    const int* __restrict__ topi, const float2* __restrict__ topw,
    int* __restrict__ elist, float* __restrict__ wlist, int* __restrict__ ecnt)
{
    __shared__ int lcnt[NE];
    __shared__ int lbase[NE];
    int tid = threadIdx.x;
    if (tid < NE) lcnt[tid] = 0;
    __syncthreads();
    int t = blockIdx.x * 256 + tid;
    int pk = topi[t];
    float2 w = topw[t];
    int e1 = pk & 0xff, e2 = (pk >> 8) & 0xff;
    int p1 = atomicAdd(&lcnt[e1], 1);
    int p2 = atomicAdd(&lcnt[e2], 1);
    __syncthreads();
    if (tid < NE) lbase[tid] = atomicAdd(&ecnt[tid], lcnt[tid]);
    __syncthreads();
    int o1 = lbase[e1] + p1;
    elist[e1 * CAP + o1] = t * 2 + 0;
    wlist[e1 * CAP + o1] = w.x;
    int o2 = lbase[e2] + p2;
    elist[e2 * CAP + o2] = t * 2 + 1;
    wlist[e2 * CAP + o2] = w.y;
}

// ---------------- finalize ----------------
__global__ __launch_bounds__(256) void finalize_kernel(
    const int* __restrict__ ecnt, const float* __restrict__ psum_part,
    float* __restrict__ out_tail)
{
    __shared__ float red[256];
    __shared__ float parts[NE];
    int tid = threadIdx.x;
    int e = tid & 7, b0 = tid >> 3;
    float s = 0.f;
    for (int b = b0; b < R1_BLK; b += 32) s += psum_part[b * NE + e];
    red[tid] = s;
    __syncthreads();
    if (tid < NE) {
        float tot = 0.f;
        #pragma unroll
        for (int j = 0; j < 32; ++j) tot += red[tid + NE * j];
        float P = tot / (float)T_TOK;
        float f = (float)ecnt[tid] / (float)(2 * T_TOK);
        parts[tid] = f * P;
        out_tail[1 + tid] = (float)ecnt[tid];
    }
    __syncthreads();
    if (tid == 0) {
        float s2 = 0.f;
        for (int i = 0; i < NE; ++i) s2 += parts[i];
        out_tail[0] = (float)NE * s2;
    }
}

// ---------------- GEMM1: 128Mx64N, BK=64, dual output (G,U) ----------------
// grid (DFF/64, CAP/128, NE); async LDS staging + XOR swizzle
__global__ __launch_bounds__(256) void gemm1_kernel(
    const unsigned short* __restrict__ xb,   // [T][DM]
    const unsigned short* __restrict__ wgb,  // [NE][DFF][DM]
    const unsigned short* __restrict__ wub,
    const int* __restrict__ elist, const int* __restrict__ ecnt,
    unsigned short* __restrict__ Hbuf)       // [2T][DFF]
{
    int e = blockIdx.z, mt = blockIdx.y, ft = blockIdx.x;
    int ne = ecnt[e];
    if (mt * 128 >= ne) return;

    __shared__ unsigned short As[128 * 64];  // chunk c=r*8+p at ushort c*8; p = l ^ (r&7)
    __shared__ unsigned short Gs[64 * 64];
    __shared__ unsigned short Us[64 * 64];
    __shared__ int tsafe[128];
    __shared__ int rawts[128];

    int tid = threadIdx.x;
    if (tid < 128) {
        int pos = mt * 128 + tid;
        int ts0 = elist[e * CAP + mt * 128];
        int ts = (pos < ne) ? elist[e * CAP + pos] : ts0;
        tsafe[tid] = ts >> 1;
        rawts[tid] = (pos < ne) ? ts : -1;
    }
    __syncthreads();

    int wave = tid >> 6, lane = tid & 63;
    int quad = lane >> 4, col = lane & 15;
    int cr = tid >> 3;                        // row-part (0..31), + j*32 per iter
    int cl = ((tid & 7) ^ (cr & 7)) * 8;      // de-swizzled global col offset (ushorts)

    const size_t woff = (size_t)e * (size_t)DFF * DM;
    const unsigned short* ap[4];
    #pragma unroll
    for (int j = 0; j < 4; ++j) ap[j] = xb + (size_t)tsafe[j * 32 + cr] * DM + cl;
    const unsigned short* gp[2];
    const unsigned short* up[2];
    #pragma unroll
    for (int j = 0; j < 2; ++j) {
        gp[j] = wgb + woff + (size_t)(ft * 64 + j * 32 + cr) * DM + cl;
        up[j] = wub + woff + (size_t)(ft * 64 + j * 32 + cr) * DM + cl;
    }
    unsigned short* lA = As + wave * 512;     // wave-uniform LDS bases
    unsigned short* lG = Gs + wave * 512;
    unsigned short* lU = Us + wave * 512;

    f32x4 accG[2][4], accU[2][4];
    #pragma unroll
    for (int i = 0; i < 2; ++i)
        #pragma unroll
        for (int n = 0; n < 4; ++n) { accG[i][n] = (f32x4){0,0,0,0}; accU[i][n] = (f32x4){0,0,0,0}; }

    for (int k0 = 0; k0 < DM; k0 += 64) {
        __syncthreads();
        #pragma unroll
        for (int j = 0; j < 4; ++j) ASYNC16(ap[j] + k0, lA + j * 2048);
        #pragma unroll
        for (int j = 0; j < 2; ++j) {
            ASYNC16(gp[j] + k0, lG + j * 2048);
            ASYNC16(up[j] + k0, lU + j * 2048);
        }
        __syncthreads();
        #pragma unroll
        for (int ksoff = 0; ksoff < 8; ksoff += 4) {
            bf16x8 a[2], g[4], u[4];
            #pragma unroll
            for (int i = 0; i < 2; ++i) {
                int m = wave * 32 + i * 16 + col;
                a[i] = *(const bf16x8*)&As[m * 64 + ((quad + ksoff) ^ (m & 7)) * 8];
            }
            #pragma unroll
            for (int n = 0; n < 4; ++n) {
                int nb = n * 16 + col;
                int off = nb * 64 + ((quad + ksoff) ^ (nb & 7)) * 8;
                g[n] = *(const bf16x8*)&Gs[off];
                u[n] = *(const bf16x8*)&Us[off];
            }
            #pragma unroll
            for (int i = 0; i < 2; ++i)
                #pragma unroll
                for (int n = 0; n < 4; ++n) {
                    accG[i][n] = __builtin_amdgcn_mfma_f32_16x16x32_bf16(a[i], g[n], accG[i][n], 0, 0, 0);
                    accU[i][n] = __builtin_amdgcn_mfma_f32_16x16x32_bf16(a[i], u[n], accU[i][n], 0, 0, 0);
                }
        }
    }
    #pragma unroll
    for (int i = 0; i < 2; ++i) {
        #pragma unroll
        for (int r = 0; r < 4; ++r) {
            int row = wave * 32 + i * 16 + quad * 4 + r;
            int ts = rawts[row];
            if (ts < 0) continue;
            unsigned short* hr = Hbuf + (size_t)ts * DFF + ft * 64 + col;
            #pragma unroll
            for (int n = 0; n < 4; ++n) {
                float gg = accG[i][n][r], uu = accU[i][n][r];
                float h = (gg / (1.f + expf(-gg))) * uu;
                hr[n * 16] = f2bf(h);
            }
        }
    }
}

// ---------------- GEMM2: 128Mx128N, BK=64 (m97 shape) ----------------
// grid (DM/128, CAP/128, NE)
__global__ __launch_bounds__(256) void gemm2_kernel(
    const unsigned short* __restrict__ Hbuf, // [2T][DFF]
    const unsigned short* __restrict__ wdb,  // [NE][DM][DFF]
    const int* __restrict__ elist, const float* __restrict__ wlist,
    const int* __restrict__ ecnt, float* __restrict__ out)
{
    int e = blockIdx.z, mt = blockIdx.y, dt = blockIdx.x;
    int ne = ecnt[e];
    if (mt * 128 >= ne) return;

    __shared__ unsigned short As[128 * 64];
    __shared__ unsigned short Bs[128 * 64];
    __shared__ int tsafe[128];
    __shared__ int rawts[128];
    __shared__ float wrow[128];

    int tid = threadIdx.x;
    if (tid < 128) {
        int pos = mt * 128 + tid;
        int ts0 = elist[e * CAP + mt * 128];
        int ts = (pos < ne) ? elist[e * CAP + pos] : ts0;
        tsafe[tid] = ts;                       // H row index
        rawts[tid] = (pos < ne) ? ts : -1;
        wrow[tid] = (pos < ne) ? wlist[e * CAP + pos] : 0.f;
    }
    __syncthreads();

    int wave = tid >> 6, lane = tid & 63;
    int quad = lane >> 4, col = lane & 15;
    int wr = (wave >> 1) * 64, wc = (wave & 1) * 64;
    int cr = tid >> 3;
    int cl = ((tid & 7) ^ (cr & 7)) * 8;

    const size_t woff = (size_t)e * (size_t)DM * DFF;
    const unsigned short* ap[4];
    const unsigned short* bp[4];
    #pragma unroll
    for (int j = 0; j < 4; ++j) {
        ap[j] = Hbuf + (size_t)tsafe[j * 32 + cr] * DFF + cl;
        bp[j] = wdb + woff + (size_t)(dt * 128 + j * 32 + cr) * DFF + cl;
    }
    unsigned short* lA = As + wave * 512;
    unsigned short* lB = Bs + wave * 512;

    f32x4 acc[4][4];
    #pragma unroll
    for (int i = 0; i < 4; ++i)
        #pragma unroll
        for (int n = 0; n < 4; ++n) acc[i][n] = (f32x4){0,0,0,0};

    for (int k0 = 0; k0 < DFF; k0 += 64) {
        __syncthreads();
        #pragma unroll
        for (int j = 0; j < 4; ++j) {
            ASYNC16(ap[j] + k0, lA + j * 2048);
            ASYNC16(bp[j] + k0, lB + j * 2048);
        }
        __syncthreads();
        #pragma unroll
        for (int ksoff = 0; ksoff < 8; ksoff += 4) {
            bf16x8 a[4], b[4];
            #pragma unroll
            for (int i = 0; i < 4; ++i) {
                int m = wr + i * 16 + col;
                a[i] = *(const bf16x8*)&As[m * 64 + ((quad + ksoff) ^ (m & 7)) * 8];
            }
            #pragma unroll
            for (int n = 0; n < 4; ++n) {
                int nb = wc + n * 16 + col;
                b[n] = *(const bf16x8*)&Bs[nb * 64 + ((quad + ksoff) ^ (nb & 7)) * 8];
            }
            #pragma unroll
            for (int i = 0; i < 4; ++i)
                #pragma unroll
                for (int n = 0; n < 4; ++n)
                    acc[i][n] = __builtin_amdgcn_mfma_f32_16x16x32_bf16(a[i], b[n], acc[i][n], 0, 0, 0);
        }
    }
    #pragma unroll
    for (int i = 0; i < 4; ++i) {
        #pragma unroll
        for (int r = 0; r < 4; ++r) {
            int row = wr + i * 16 + quad * 4 + r;
            int ts = rawts[row];
            if (ts < 0) continue;
            int t = ts >> 1;
            float w = wrow[row];
            float* orow = out + (size_t)t * DM + dt * 128 + wc + col;
            #pragma unroll
            for (int n = 0; n < 4; ++n)
                atomicAdd(orow + n * 16, w * acc[i][n][r]);
        }
    }
}

extern "C" void kernel_launch(void* const* d_in, const int* in_sizes, int n_in,
                              void* d_out, int out_size, void* d_ws, size_t ws_size,
                              hipStream_t stream) {
    const float* x      = (const float*)d_in[0];
    const float* gate_w = (const float*)d_in[1];
    const float* w_gate = (const float*)d_in[2];
    const float* w_up   = (const float*)d_in[3];
    const float* w_down = (const float*)d_in[4];
    float* out = (float*)d_out;

    char* p = (char*)d_ws;
    unsigned short* xb   = (unsigned short*)p; p += (size_t)T_TOK * DM * 2;
    unsigned short* wgb  = (unsigned short*)p; p += (size_t)NE * DFF * DM * 2;
    unsigned short* wub  = (unsigned short*)p; p += (size_t)NE * DFF * DM * 2;
    unsigned short* wdb  = (unsigned short*)p; p += (size_t)NE * DM * DFF * 2;
    unsigned short* Hbuf = (unsigned short*)p; p += (size_t)2 * T_TOK * DFF * 2;
    int*   elist = (int*)p;   p += (size_t)NE * CAP * 4;
    float* wlist = (float*)p; p += (size_t)NE * CAP * 4;
    int*   ecnt  = (int*)p;   p += NE * 4;
    int*   topi  = (int*)p;   p += (size_t)T_TOK * 4;
    float2* topw = (float2*)p; p += (size_t)T_TOK * 8;
    float* psum_part = (float*)p; p += (size_t)R1_BLK * NE * 4;

    hipMemsetAsync(d_out, 0, (size_t)out_size * 4, stream);
    hipMemsetAsync(ecnt, 0, NE * 4, stream);

    const int nW = NE * DFF * DM;
    cvt_kernel<<<(nW / 4 + 255) / 256, 256, 0, stream>>>(w_gate, wgb, nW);
    cvt_kernel<<<(nW / 4 + 255) / 256, 256, 0, stream>>>(w_up, wub, nW);
    cvt_kernel<<<(nW / 4 + 255) / 256, 256, 0, stream>>>(w_down, wdb, nW);

    router_kernel<<<R1_BLK, 256, 0, stream>>>(x, gate_w, xb, topi, topw, psum_part);
    scatter_kernel<<<T_TOK / 256, 256, 0, stream>>>(topi, topw, elist, wlist, ecnt);
    finalize_kernel<<<1, 256, 0, stream>>>(ecnt, psum_part, out + (size_t)T_TOK * DM);

    gemm1_kernel<<<dim3(DFF / 64, CAP / 128, NE), 256, 0, stream>>>(xb, wgb, wub, elist, ecnt, Hbuf);
    gemm2_kernel<<<dim3(DM / 128, CAP / 128, NE), 256, 0, stream>>>(Hbuf, wdb, elist, wlist, ecnt, out);
}

// Round 4
// 347.716 us; speedup vs baseline: 1.8952x; 1.0956x over previous
//
#include <hip/hip_runtime.h>

// MoE: T=8192, D_MODEL=1024, D_FF=1024, E=8, top-2.
// Router fp32; FFN bf16 MFMA (m97-style async staging + XOR swizzle).
// R4: atomic-free gemm2 -> per-slot eo buffer + vectorized combine kernel.

#define T_TOK   8192
#define DM      1024
#define DFF     1024
#define NE      8
#define CAP     16384
#define R1_BLK  (T_TOK / 4)

typedef __attribute__((ext_vector_type(8))) short bf16x8;
typedef __attribute__((ext_vector_type(4))) float f32x4;

#define ASYNC16(gp, lp) __builtin_amdgcn_global_load_lds( \
    (const __attribute__((address_space(1))) unsigned int*)(gp), \
    (__attribute__((address_space(3))) unsigned int*)(lp), 16, 0, 0)

__device__ __forceinline__ unsigned short f2bf(float f) {
    union { float f; unsigned u; } c; c.f = f;
    unsigned r = c.u + 0x7fffu + ((c.u >> 16) & 1u);
    return (unsigned short)(r >> 16);
}
__device__ __forceinline__ float bf2f(unsigned short h) {
    union { unsigned u; float f; } c; c.u = ((unsigned)h) << 16;
    return c.f;
}

// ---------------- fp32 -> bf16: all three weight tensors in one launch ----------------
__global__ __launch_bounds__(256) void cvt3_kernel(
    const float* __restrict__ s0, const float* __restrict__ s1, const float* __restrict__ s2,
    unsigned short* __restrict__ d0, unsigned short* __restrict__ d1, unsigned short* __restrict__ d2)
{
    int idx = blockIdx.x * 256 + threadIdx.x;      // one float4 per thread
    int seg = idx >> 21;                           // NE*DFF*DM/4 = 2^21 per tensor
    int off = (idx & ((1 << 21) - 1)) * 4;
    const float* s = (seg == 0) ? s0 : (seg == 1) ? s1 : s2;
    unsigned short* d = (seg == 0) ? d0 : (seg == 1) ? d1 : d2;
    float4 v = *(const float4*)(s + off);
    ushort4 o;
    o.x = f2bf(v.x); o.y = f2bf(v.y); o.z = f2bf(v.z); o.w = f2bf(v.w);
    *(ushort4*)(d + off) = o;
}

// ---------------- R1: router math (fp32) + x->bf16 fuse ----------------
__global__ __launch_bounds__(256) void router_kernel(
    const float* __restrict__ x, const float* __restrict__ gate_w,
    unsigned short* __restrict__ xb,
    int* __restrict__ topi, float2* __restrict__ topw,
    float* __restrict__ psum_part)
{
    __shared__ float gw[NE * DM];
    __shared__ float blk_psum[NE];
    int tid = threadIdx.x;
    for (int i = tid; i < NE * DM; i += 256) gw[i] = gate_w[i];
    if (tid < NE) blk_psum[tid] = 0.f;
    __syncthreads();

    int wv = tid >> 6, lane = tid & 63;
    int t = blockIdx.x * 4 + wv;

    float acc[NE];
    #pragma unroll
    for (int e = 0; e < NE; ++e) acc[e] = 0.f;
    const float* xr = x + (size_t)t * DM;
    unsigned short* xbr = xb + (size_t)t * DM;
    #pragma unroll 4
    for (int i = 0; i < DM / 64; ++i) {
        float xv = xr[i * 64 + lane];
        xbr[i * 64 + lane] = f2bf(xv);
        #pragma unroll
        for (int e = 0; e < NE; ++e)
            acc[e] += xv * gw[e * DM + i * 64 + lane];
    }
    #pragma unroll
    for (int e = 0; e < NE; ++e) {
        float v = acc[e];
        #pragma unroll
        for (int s = 32; s > 0; s >>= 1) v += __shfl_xor(v, s, 64);
        acc[e] = v;
    }
    if (lane == 0) {
        float mx = acc[0];
        #pragma unroll
        for (int e = 1; e < NE; ++e) mx = fmaxf(mx, acc[e]);
        float p[NE], sum = 0.f;
        #pragma unroll
        for (int e = 0; e < NE; ++e) { p[e] = expf(acc[e] - mx); sum += p[e]; }
        float inv = 1.f / sum;
        #pragma unroll
        for (int e = 0; e < NE; ++e) { p[e] *= inv; atomicAdd(&blk_psum[e], p[e]); }
        int i1 = 0; float v1 = p[0];
        #pragma unroll
        for (int e = 1; e < NE; ++e) if (p[e] > v1) { v1 = p[e]; i1 = e; }
        int i2 = -1; float v2 = -1.f;
        #pragma unroll
        for (int e = 0; e < NE; ++e) { if (e == i1) continue; if (p[e] > v2) { v2 = p[e]; i2 = e; } }
        float winv = 1.f / (v1 + v2);
        topi[t] = i1 | (i2 << 8);
        topw[t] = make_float2(v1 * winv, v2 * winv);
    }
    __syncthreads();
    if (tid < NE) psum_part[blockIdx.x * NE + tid] = blk_psum[tid];
}

// ---------------- R2: scatter into per-expert lists ----------------
__global__ __launch_bounds__(256) void scatter_kernel(
    const int* __restrict__ topi,
    int* __restrict__ elist, int* __restrict__ ecnt)
{
    __shared__ int lcnt[NE];
    __shared__ int lbase[NE];
    int tid = threadIdx.x;
    if (tid < NE) lcnt[tid] = 0;
    __syncthreads();
    int t = blockIdx.x * 256 + tid;
    int pk = topi[t];
    int e1 = pk & 0xff, e2 = (pk >> 8) & 0xff;
    int p1 = atomicAdd(&lcnt[e1], 1);
    int p2 = atomicAdd(&lcnt[e2], 1);
    __syncthreads();
    if (tid < NE) lbase[tid] = atomicAdd(&ecnt[tid], lcnt[tid]);
    __syncthreads();
    elist[e1 * CAP + lbase[e1] + p1] = t * 2 + 0;
    elist[e2 * CAP + lbase[e2] + p2] = t * 2 + 1;
}

// ---------------- finalize ----------------
__global__ __launch_bounds__(256) void finalize_kernel(
    const int* __restrict__ ecnt, const float* __restrict__ psum_part,
    float* __restrict__ out_tail)
{
    __shared__ float red[256];
    __shared__ float parts[NE];
    int tid = threadIdx.x;
    int e = tid & 7, b0 = tid >> 3;
    float s = 0.f;
    for (int b = b0; b < R1_BLK; b += 32) s += psum_part[b * NE + e];
    red[tid] = s;
    __syncthreads();
    if (tid < NE) {
        float tot = 0.f;
        #pragma unroll
        for (int j = 0; j < 32; ++j) tot += red[tid + NE * j];
        float P = tot / (float)T_TOK;
        float f = (float)ecnt[tid] / (float)(2 * T_TOK);
        parts[tid] = f * P;
        out_tail[1 + tid] = (float)ecnt[tid];
    }
    __syncthreads();
    if (tid == 0) {
        float s2 = 0.f;
        for (int i = 0; i < NE; ++i) s2 += parts[i];
        out_tail[0] = (float)NE * s2;
    }
}

// ---------------- GEMM1: 128Mx64N, BK=64, dual output (G,U) ----------------
__global__ __launch_bounds__(256) void gemm1_kernel(
    const unsigned short* __restrict__ xb,   // [T][DM]
    const unsigned short* __restrict__ wgb,  // [NE][DFF][DM]
    const unsigned short* __restrict__ wub,
    const int* __restrict__ elist, const int* __restrict__ ecnt,
    unsigned short* __restrict__ Hbuf)       // [2T][DFF]
{
    int e = blockIdx.z, mt = blockIdx.y, ft = blockIdx.x;
    int ne = ecnt[e];
    if (mt * 128 >= ne) return;

    __shared__ unsigned short As[128 * 64];
    __shared__ unsigned short Gs[64 * 64];
    __shared__ unsigned short Us[64 * 64];
    __shared__ int tsafe[128];
    __shared__ int rawts[128];

    int tid = threadIdx.x;
    if (tid < 128) {
        int pos = mt * 128 + tid;
        int ts0 = elist[e * CAP + mt * 128];
        int ts = (pos < ne) ? elist[e * CAP + pos] : ts0;
        tsafe[tid] = ts >> 1;
        rawts[tid] = (pos < ne) ? ts : -1;
    }
    __syncthreads();

    int wave = tid >> 6, lane = tid & 63;
    int quad = lane >> 4, col = lane & 15;
    int cr = tid >> 3;
    int cl = ((tid & 7) ^ (cr & 7)) * 8;

    const size_t woff = (size_t)e * (size_t)DFF * DM;
    const unsigned short* ap[4];
    #pragma unroll
    for (int j = 0; j < 4; ++j) ap[j] = xb + (size_t)tsafe[j * 32 + cr] * DM + cl;
    const unsigned short* gp[2];
    const unsigned short* up[2];
    #pragma unroll
    for (int j = 0; j < 2; ++j) {
        gp[j] = wgb + woff + (size_t)(ft * 64 + j * 32 + cr) * DM + cl;
        up[j] = wub + woff + (size_t)(ft * 64 + j * 32 + cr) * DM + cl;
    }
    unsigned short* lA = As + wave * 512;
    unsigned short* lG = Gs + wave * 512;
    unsigned short* lU = Us + wave * 512;

    f32x4 accG[2][4], accU[2][4];
    #pragma unroll
    for (int i = 0; i < 2; ++i)
        #pragma unroll
        for (int n = 0; n < 4; ++n) { accG[i][n] = (f32x4){0,0,0,0}; accU[i][n] = (f32x4){0,0,0,0}; }

    for (int k0 = 0; k0 < DM; k0 += 64) {
        __syncthreads();
        #pragma unroll
        for (int j = 0; j < 4; ++j) ASYNC16(ap[j] + k0, lA + j * 2048);
        #pragma unroll
        for (int j = 0; j < 2; ++j) {
            ASYNC16(gp[j] + k0, lG + j * 2048);
            ASYNC16(up[j] + k0, lU + j * 2048);
        }
        __syncthreads();
        #pragma unroll
        for (int ksoff = 0; ksoff < 8; ksoff += 4) {
            bf16x8 a[2], g[4], u[4];
            #pragma unroll
            for (int i = 0; i < 2; ++i) {
                int m = wave * 32 + i * 16 + col;
                a[i] = *(const bf16x8*)&As[m * 64 + ((quad + ksoff) ^ (m & 7)) * 8];
            }
            #pragma unroll
            for (int n = 0; n < 4; ++n) {
                int nb = n * 16 + col;
                int off = nb * 64 + ((quad + ksoff) ^ (nb & 7)) * 8;
                g[n] = *(const bf16x8*)&Gs[off];
                u[n] = *(const bf16x8*)&Us[off];
            }
            #pragma unroll
            for (int i = 0; i < 2; ++i)
                #pragma unroll
                for (int n = 0; n < 4; ++n) {
                    accG[i][n] = __builtin_amdgcn_mfma_f32_16x16x32_bf16(a[i], g[n], accG[i][n], 0, 0, 0);
                    accU[i][n] = __builtin_amdgcn_mfma_f32_16x16x32_bf16(a[i], u[n], accU[i][n], 0, 0, 0);
                }
        }
    }
    #pragma unroll
    for (int i = 0; i < 2; ++i) {
        #pragma unroll
        for (int r = 0; r < 4; ++r) {
            int row = wave * 32 + i * 16 + quad * 4 + r;
            int ts = rawts[row];
            if (ts < 0) continue;
            unsigned short* hr = Hbuf + (size_t)ts * DFF + ft * 64 + col;
            #pragma unroll
            for (int n = 0; n < 4; ++n) {
                float gg = accG[i][n][r], uu = accU[i][n][r];
                float h = (gg / (1.f + expf(-gg))) * uu;
                hr[n * 16] = f2bf(h);
            }
        }
    }
}

// ---------------- GEMM2: 128Mx128N, BK=64 -> eo (bf16, unweighted, no atomics) --------
__global__ __launch_bounds__(256) void gemm2_kernel(
    const unsigned short* __restrict__ Hbuf, // [2T][DFF]
    const unsigned short* __restrict__ wdb,  // [NE][DM][DFF]
    const int* __restrict__ elist, const int* __restrict__ ecnt,
    unsigned short* __restrict__ eo)         // [2T][DM]
{
    int e = blockIdx.z, mt = blockIdx.y, dt = blockIdx.x;
    int ne = ecnt[e];
    if (mt * 128 >= ne) return;

    __shared__ unsigned short As[128 * 64];
    __shared__ unsigned short Bs[128 * 64];
    __shared__ int tsafe[128];
    __shared__ int rawts[128];

    int tid = threadIdx.x;
    if (tid < 128) {
        int pos = mt * 128 + tid;
        int ts0 = elist[e * CAP + mt * 128];
        int ts = (pos < ne) ? elist[e * CAP + pos] : ts0;
        tsafe[tid] = ts;
        rawts[tid] = (pos < ne) ? ts : -1;
    }
    __syncthreads();

    int wave = tid >> 6, lane = tid & 63;
    int quad = lane >> 4, col = lane & 15;
    int wr = (wave >> 1) * 64, wc = (wave & 1) * 64;
    int cr = tid >> 3;
    int cl = ((tid & 7) ^ (cr & 7)) * 8;

    const size_t woff = (size_t)e * (size_t)DM * DFF;
    const unsigned short* ap[4];
    const unsigned short* bp[4];
    #pragma unroll
    for (int j = 0; j < 4; ++j) {
        ap[j] = Hbuf + (size_t)tsafe[j * 32 + cr] * DFF + cl;
        bp[j] = wdb + woff + (size_t)(dt * 128 + j * 32 + cr) * DFF + cl;
    }
    unsigned short* lA = As + wave * 512;
    unsigned short* lB = Bs + wave * 512;

    f32x4 acc[4][4];
    #pragma unroll
    for (int i = 0; i < 4; ++i)
        #pragma unroll
        for (int n = 0; n < 4; ++n) acc[i][n] = (f32x4){0,0,0,0};

    for (int k0 = 0; k0 < DFF; k0 += 64) {
        __syncthreads();
        #pragma unroll
        for (int j = 0; j < 4; ++j) {
            ASYNC16(ap[j] + k0, lA + j * 2048);
            ASYNC16(bp[j] + k0, lB + j * 2048);
        }
        __syncthreads();
        #pragma unroll
        for (int ksoff = 0; ksoff < 8; ksoff += 4) {
            bf16x8 a[4], b[4];
            #pragma unroll
            for (int i = 0; i < 4; ++i) {
                int m = wr + i * 16 + col;
                a[i] = *(const bf16x8*)&As[m * 64 + ((quad + ksoff) ^ (m & 7)) * 8];
            }
            #pragma unroll
            for (int n = 0; n < 4; ++n) {
                int nb = wc + n * 16 + col;
                b[n] = *(const bf16x8*)&Bs[nb * 64 + ((quad + ksoff) ^ (nb & 7)) * 8];
            }
            #pragma unroll
            for (int i = 0; i < 4; ++i)
                #pragma unroll
                for (int n = 0; n < 4; ++n)
                    acc[i][n] = __builtin_amdgcn_mfma_f32_16x16x32_bf16(a[i], b[n], acc[i][n], 0, 0, 0);
        }
    }
    #pragma unroll
    for (int i = 0; i < 4; ++i) {
        #pragma unroll
        for (int r = 0; r < 4; ++r) {
            int row = wr + i * 16 + quad * 4 + r;
            int ts = rawts[row];
            if (ts < 0) continue;
            unsigned short* er = eo + (size_t)ts * DM + dt * 128 + wc + col;
            #pragma unroll
            for (int n = 0; n < 4; ++n)
                er[n * 16] = f2bf(acc[i][n][r]);
        }
    }
}

// ---------------- combine: out[t] = w1*eo[2t] + w2*eo[2t+1] ----------------
__global__ __launch_bounds__(256) void combine_kernel(
    const unsigned short* __restrict__ eo, const float2* __restrict__ topw,
    float* __restrict__ out)
{
    int idx = blockIdx.x * 256 + threadIdx.x;   // 8 output elems per thread
    int t = idx >> 7;
    int c = (idx & 127) << 3;
    float2 w = topw[t];
    const unsigned short* e0 = eo + (size_t)(t * 2) * DM + c;
    ushort4 a0 = *(const ushort4*)e0;
    ushort4 a1 = *(const ushort4*)(e0 + 4);
    ushort4 b0 = *(const ushort4*)(e0 + DM);
    ushort4 b1 = *(const ushort4*)(e0 + DM + 4);
    float* orow = out + (size_t)t * DM + c;
    float4 o0, o1;
    o0.x = w.x * bf2f(a0.x) + w.y * bf2f(b0.x);
    o0.y = w.x * bf2f(a0.y) + w.y * bf2f(b0.y);
    o0.z = w.x * bf2f(a0.z) + w.y * bf2f(b0.z);
    o0.w = w.x * bf2f(a0.w) + w.y * bf2f(b0.w);
    o1.x = w.x * bf2f(a1.x) + w.y * bf2f(b1.x);
    o1.y = w.x * bf2f(a1.y) + w.y * bf2f(b1.y);
    o1.z = w.x * bf2f(a1.z) + w.y * bf2f(b1.z);
    o1.w = w.x * bf2f(a1.w) + w.y * bf2f(b1.w);
    *(float4*)orow = o0;
    *(float4*)(orow + 4) = o1;
}

extern "C" void kernel_launch(void* const* d_in, const int* in_sizes, int n_in,
                              void* d_out, int out_size, void* d_ws, size_t ws_size,
                              hipStream_t stream) {
    const float* x      = (const float*)d_in[0];
    const float* gate_w = (const float*)d_in[1];
    const float* w_gate = (const float*)d_in[2];
    const float* w_up   = (const float*)d_in[3];
    const float* w_down = (const float*)d_in[4];
    float* out = (float*)d_out;

    char* p = (char*)d_ws;
    unsigned short* xb   = (unsigned short*)p; p += (size_t)T_TOK * DM * 2;
    unsigned short* wgb  = (unsigned short*)p; p += (size_t)NE * DFF * DM * 2;
    unsigned short* wub  = (unsigned short*)p; p += (size_t)NE * DFF * DM * 2;
    unsigned short* wdb  = (unsigned short*)p; p += (size_t)NE * DM * DFF * 2;
    unsigned short* Hbuf = (unsigned short*)p; p += (size_t)2 * T_TOK * DFF * 2;
    int*   elist = (int*)p;   p += (size_t)NE * CAP * 4;
    int*   ecnt  = (int*)p;   p += NE * 4;
    int*   topi  = (int*)p;   p += (size_t)T_TOK * 4;
    float2* topw = (float2*)p; p += (size_t)T_TOK * 8;
    float* psum_part = (float*)p; p += (size_t)R1_BLK * NE * 4;
    // eo aliases wgb+wub (dead after gemm1): [2T][DM] bf16 = 33.5 MB
    unsigned short* eo = wgb;

    hipMemsetAsync(ecnt, 0, NE * 4, stream);

    cvt3_kernel<<<3 * (NE * DFF * DM / 4) / 256, 256, 0, stream>>>(
        w_gate, w_up, w_down, wgb, wub, wdb);

    router_kernel<<<R1_BLK, 256, 0, stream>>>(x, gate_w, xb, topi, topw, psum_part);
    scatter_kernel<<<T_TOK / 256, 256, 0, stream>>>(topi, elist, ecnt);
    finalize_kernel<<<1, 256, 0, stream>>>(ecnt, psum_part, out + (size_t)T_TOK * DM);

    gemm1_kernel<<<dim3(DFF / 64, CAP / 128, NE), 256, 0, stream>>>(xb, wgb, wub, elist, ecnt, Hbuf);
    gemm2_kernel<<<dim3(DM / 128, CAP / 128, NE), 256, 0, stream>>>(Hbuf, wdb, elist, ecnt, eo);
    combine_kernel<<<T_TOK * DM / 8 / 256, 256, 0, stream>>>(eo, topw, out);
}